// Round 23
// baseline (40.724 us; speedup 1.0000x reference)
//
#include <hip/hip_runtime.h>

// Depthwise cross-correlation, B*C = 32768 planes: x[32][32] (*) k[8][8] -> out[25][25].
// softmax(weight) sums to 1.0 -> output == correlation; weight unused.
//
// Round-23 = round-22 (barrier-free MFMA Toeplitz, one wave = one plane-region)
// with a 2-DEEP PER-WAVE PIPELINE: each wave processes planes p0 = blk*8+wave
// and p1 = p0+4 in its SINGLE LDS region. Sequence: load p0 -> write LDS ->
// ISSUE p1 loads (no wait) -> compute+store p0 (p1's HBM latency hides under
// ~1500 cyc of LDS+MFMA) -> write p1 into the same region (same-wave DS ops
// execute in order -> write-after-read safe, no dbuf, no barrier) -> compute
// p1. LDS/occupancy identical to r22 (18.9 KB, 8 blocks/CU, 32 waves/CU).
// Discriminates latency-bound (expect ~35us) vs delivered-BW-bound (~40us:
// 224MB combined / 40us = 5.6 TB/s = 89% of the 6.3 TB/s copy ceiling).
// Math per plane identical to r20/r21/r22.

#define NPLANES (128 * 256)
#define PPB 8                       // planes per block (2 per wave)
#define RST 20                      // x row stride (dwords), %4==0 for b128
#define XROWS 40                    // 32 data + 8 garbage-pad rows
#define XP (XROWS * RST)            // 800
#define TAPB (4 * XP)               // 3200 (4 waves x one x-region)
#define TKY 48                      // per-ky tap row: 24 dw E + 24 dw O
#define TPP (8 * TKY)               // 384 dw per wave
#define LDS_DW (TAPB + 4 * TPP)     // 4736 dw = 18944 B -> 8 blocks/CU
#define OH 25
#define OW 25

typedef __attribute__((ext_vector_type(8))) short short8;    // 8 bf16 (4 VGPR)
typedef __attribute__((ext_vector_type(4))) float f32x4;     // MFMA acc
typedef __attribute__((ext_vector_type(4))) unsigned uint4v;

__device__ __forceinline__ unsigned cvt_pk_bf16(float a, float b) {
    unsigned r;  // lo = bf16(a), hi = bf16(b)
    asm("v_cvt_pk_bf16_f32 %0, %1, %2" : "=v"(r) : "v"(a), "v"(b));
    return r;
}

// ---- per-wave staging writes (x rows + nonzero tap quads) ----
__device__ __forceinline__ void write_x(unsigned* xbase,
                                        const float4& v0, const float4& v1,
                                        const float4& v2, const float4& v3) {
    uint4v w;
    w.x = cvt_pk_bf16(v0.x, v0.y); w.y = cvt_pk_bf16(v0.z, v0.w);
    w.z = cvt_pk_bf16(v1.x, v1.y); w.w = cvt_pk_bf16(v1.z, v1.w);
    *reinterpret_cast<uint4v*>(xbase + 0) = w;
    w.x = cvt_pk_bf16(v2.x, v2.y); w.y = cvt_pk_bf16(v2.z, v2.w);
    w.z = cvt_pk_bf16(v3.x, v3.y); w.w = cvt_pk_bf16(v3.z, v3.w);
    *reinterpret_cast<uint4v*>(xbase + 4) = w;
}
__device__ __forceinline__ void write_taps(unsigned* ldsu, int tb0, int ky, int q,
                                           const float4& v0, const float4& v1) {
    uint4v m;
    int off;
    if (q == 0) {            // E[8..11] = packed even pairs
        m.x = cvt_pk_bf16(v0.x, v0.y); m.y = cvt_pk_bf16(v0.z, v0.w);
        m.z = cvt_pk_bf16(v1.x, v1.y); m.w = cvt_pk_bf16(v1.z, v1.w);
        off = 8;
    } else if (q == 1) {     // O[4..7] = (0,0,0,(pad,tap0))
        m.x = 0u; m.y = 0u; m.z = 0u;
        m.w = cvt_pk_bf16(0.f, v0.x);
        off = 28;
    } else {                 // O[8..11] = odd-shifted pairs
        m.x = cvt_pk_bf16(v0.y, v0.z); m.y = cvt_pk_bf16(v0.w, v1.x);
        m.z = cvt_pk_bf16(v1.y, v1.z); m.w = cvt_pk_bf16(v1.w, 0.f);
        off = 32;
    }
    *reinterpret_cast<uint4v*>(&ldsu[tb0 + ky * TKY + off]) = m;
}

// ---- per-plane compute + store (identical math to r20/r21/r22) ----
__device__ __forceinline__ void compute_plane(const unsigned* xb, const unsigned* tb,
                                              int off0, int off1, int c, int a,
                                              float* op) {
    f32x4 acc00 = {0.f, 0.f, 0.f, 0.f};
    f32x4 acc01 = {0.f, 0.f, 0.f, 0.f};
    f32x4 acc10 = {0.f, 0.f, 0.f, 0.f};
    f32x4 acc11 = {0.f, 0.f, 0.f, 0.f};
#pragma unroll
    for (int ky = 0; ky < 8; ++ky) {
        const short8 a0 =
            *reinterpret_cast<const short8*>(xb + (ky + c) * RST);
        const short8 a1 =
            *reinterpret_cast<const short8*>(xb + (16 + ky + c) * RST);
        const unsigned* bp = tb + ky * TKY;
        uint4v bu0, bu1;
        bu0.x = bp[off0 + 0]; bu0.y = bp[off0 + 1];
        bu0.z = bp[off0 + 2]; bu0.w = bp[off0 + 3];
        bu1.x = bp[off1 + 0]; bu1.y = bp[off1 + 1];
        bu1.z = bp[off1 + 2]; bu1.w = bp[off1 + 3];
        const short8 b0 = __builtin_bit_cast(short8, bu0);
        const short8 b1 = __builtin_bit_cast(short8, bu1);
        acc00 = __builtin_amdgcn_mfma_f32_16x16x32_bf16(a0, b0, acc00, 0, 0, 0);
        acc01 = __builtin_amdgcn_mfma_f32_16x16x32_bf16(a0, b1, acc01, 0, 0, 0);
        acc10 = __builtin_amdgcn_mfma_f32_16x16x32_bf16(a1, b0, acc10, 0, 0, 0);
        acc11 = __builtin_amdgcn_mfma_f32_16x16x32_bf16(a1, b1, acc11, 0, 0, 0);
    }
#pragma unroll
    for (int reg = 0; reg < 4; ++reg) {
        const int r0 = 4 * a + reg;              // 0..15
        op[r0 * OW + c] = acc00[reg];
        if (c <= 8) op[r0 * OW + 16 + c] = acc01[reg];
        if (r0 <= 8) {
            op[(16 + r0) * OW + c] = acc10[reg];
            if (c <= 8) op[(16 + r0) * OW + 16 + c] = acc11[reg];
        }
    }
}

__global__ __launch_bounds__(256)
void dwxcorr_kernel(const float* __restrict__ x,
                    const float* __restrict__ kern,
                    float* __restrict__ out) {
    __shared__ unsigned ldsu[LDS_DW];
    const int tid  = threadIdx.x;
    const int wave = tid >> 6;
    const int l    = tid & 63;
    const int p0   = blockIdx.x * PPB + wave;    // planes p0 and p0+4
    const int p1   = p0 + 4;

    // lane staging geometry
    const int row  = l >> 1;
    const int half = l & 1;
    const int tky  = l / 3;          // tap lanes l<24
    const int tq   = l - 3 * tky;

    unsigned* xbase = &ldsu[wave * XP + row * RST + half * 8];
    const int tb0 = TAPB + wave * TPP;

    // ---- one-time zero-fill of tap pads (zeros persist across both phases;
    //      the 3 nonzero quads/ky are rewritten each phase) ----
    {
        const uint4v z4 = {0u, 0u, 0u, 0u};
        *reinterpret_cast<uint4v*>(&ldsu[tb0 + 4 * l]) = z4;
        *reinterpret_cast<uint2*>(&ldsu[tb0 + 256 + 2 * l]) = make_uint2(0u, 0u);
    }

    // ---- Phase A loads: plane p0 ----
    const float* gx0 = x + (size_t)p0 * 1024 + row * 32 + half * 16;
    float4 a0 = *reinterpret_cast<const float4*>(gx0 + 0);
    float4 a1 = *reinterpret_cast<const float4*>(gx0 + 4);
    float4 a2 = *reinterpret_cast<const float4*>(gx0 + 8);
    float4 a3 = *reinterpret_cast<const float4*>(gx0 + 12);
    float4 t0, t1;
    if (l < 24) {
        const float* gk0 = kern + (size_t)p0 * 64 + tky * 8;
        t0 = *reinterpret_cast<const float4*>(gk0 + 0);
        t1 = *reinterpret_cast<const float4*>(gk0 + 4);
    }
    // write p0 into LDS (vmcnt waits on p0 loads here)
    write_x(xbase, a0, a1, a2, a3);
    if (l < 24) write_taps(ldsu, tb0, tky, tq, t0, t1);

    // ---- Issue phase-B loads: plane p1 (no wait; hides under compute p0) ----
    const float* gx1 = x + (size_t)p1 * 1024 + row * 32 + half * 16;
    float4 b0 = *reinterpret_cast<const float4*>(gx1 + 0);
    float4 b1 = *reinterpret_cast<const float4*>(gx1 + 4);
    float4 b2 = *reinterpret_cast<const float4*>(gx1 + 8);
    float4 b3 = *reinterpret_cast<const float4*>(gx1 + 12);
    float4 u0, u1;
    if (l < 24) {
        const float* gk1 = kern + (size_t)p1 * 64 + tky * 8;
        u0 = *reinterpret_cast<const float4*>(gk1 + 0);
        u1 = *reinterpret_cast<const float4*>(gk1 + 4);
    }

    // wave-local fence: own LDS writes -> own reads
    asm volatile("s_waitcnt lgkmcnt(0)" ::: "memory");
    __builtin_amdgcn_sched_barrier(0);

    // ---- Compute p0 ----
    const int c = l & 15;
    const int a = l >> 4;
    const unsigned* xb = &ldsu[wave * XP + 4 * a];
    const unsigned* tb = &ldsu[tb0];
    int off0, off1;
    {
        int s = 8 * a - c;
        int st = (s >> 1) + 8;
        st = st < 0 ? 0 : (st > 20 ? 20 : st);
        off0 = (s & 1) * 24 + st;
        s = 8 * a - 16 - c;
        st = (s >> 1) + 8;
        st = st < 0 ? 0 : (st > 20 ? 20 : st);
        off1 = (s & 1) * 24 + st;
    }
    compute_plane(xb, tb, off0, off1, c, a, out + (size_t)p0 * (OH * OW));

    // ---- Write p1 into the SAME LDS region (same-wave DS ops are in-order:
    //      these writes cannot pass the compute-p0 reads above) ----
    write_x(xbase, b0, b1, b2, b3);
    if (l < 24) write_taps(ldsu, tb0, tky, tq, u0, u1);

    asm volatile("s_waitcnt lgkmcnt(0)" ::: "memory");
    __builtin_amdgcn_sched_barrier(0);

    // ---- Compute p1 ----
    compute_plane(xb, tb, off0, off1, c, a, out + (size_t)p1 * (OH * OW));
}

extern "C" void kernel_launch(void* const* d_in, const int* in_sizes, int n_in,
                              void* d_out, int out_size, void* d_ws, size_t ws_size,
                              hipStream_t stream) {
    const float* x = (const float*)d_in[0];
    const float* k = (const float*)d_in[1];
    // d_in[2] (weight) unused: softmax weights sum to exactly 1.
    float* out = (float*)d_out;
    const int nblocks = NPLANES / PPB;   // 4096
    dwxcorr_kernel<<<nblocks, 256, 0, stream>>>(x, k, out);
}